// Round 6
// baseline (231.574 us; speedup 1.0000x reference)
//
#include <hip/hip_runtime.h>

// GraphSAGE: 2x SAGEConv(mean) + Linear + softmax.
// Pipeline (5 dispatches): memset(gtail) ->
//   bucket_prep (phase-A LDS bucket-sort of edges | cvt x->bf16 | pack W frags)
//   -> fill_csr (per-bucket CSR build, 2-pass, src-range-grouped, emits cnt4)
//   -> fused_l1 (range-phased paired gather + dual MFMA GEMM + relu -> h0)
//   -> fused_l2 (same gather + dual GEMM + relu + out-proj + softmax).
//
// This round: RANGE-PHASED GATHER WITH R2 EXECUTION DISCIPLINE.
// Evidence: R4 proved range-phasing cuts FETCH 140->60MB (L2-resident slices),
// but its guarded per-segment loops (~4 edges each, conditional loads) killed
// MLP (VALUBusy 13%, 0.6TB/s). R2's regime (dense unconditional clamped 256B
// loads, 8+ in flight) is the efficient execution. Combine both:
//   - per quarter-wave, nodes processed in PAIRS: for each src-range r, issue
//     node A's and node B's padded 8-slot batches together -> 16 unconditional
//     row loads in flight, uniform control flow; pad slots clamp to the
//     segment's last row (same cache line, ~free) and are zero-masked.
//   - accumulators are four NAMED arrays (a0..a3): all static indexing.
//   - r-loop outermost: ~768 co-resident blocks sweep the 4 x ~4MB table
//     slices in phase -> per-XCD L2-resident (R4-proven mechanism).
// fill_csr = R4's two-pass build emitting packed cnt4 (4 x u8 range lengths);
// placement window [min(pref,CAP), min(pref+c,CAP)) matches gather exactly.
//
// CSR build: bucket = dst>>8. Phase A: per-block LDS histogram + scan + ~196
// global atomics reserving per-(XCD,bucket) segments (b&7 XCD heuristic),
// LDS-sorted dump. Phase B: one block per bucket, count/(node,range) ->
// prefix -> LDS-atomic placement, coalesced 32KB tile dump.
//
// Dual GEMM as one K=256 MFMA GEMM: A_cat=[agg|root] bf16, W_cat=[Wl;Wr] packed.
// mfma_f32_16x16x32_bf16: A[m=lane&15][k=(lane>>4)*8+j]; B[k][n=lane&15];
// C: col=lane&15, row=(lane>>4)*4+reg (m89/m91-verified layouts).
// Zero barriers in the fused kernels (wave-private LDS tiles, DS wave-ordered).

#define CAP 64
#define NBK 256      // bucket table stride (max buckets; N<=65536)
#define EPB 2048     // edges per phase-A block (8 per thread)
#define BCAP8 768    // per-(XCD,bucket) segment capacity (mean ~510, ~11 sigma)
#define ASTR 136     // LDS A-tile row stride in ushorts (272B = 17x16B)
#define NR 4         // src ranges for L2 phasing
#define RSH 14       // range = src >> 14

typedef __attribute__((ext_vector_type(8))) short bf16x8;
typedef __attribute__((ext_vector_type(4))) float f32x4;

__device__ __forceinline__ unsigned short bf16_rtne(float f) {
    unsigned u = __float_as_uint(f);
    u += 0x7FFFu + ((u >> 16) & 1u);
    return (unsigned short)(u >> 16);
}

__device__ __forceinline__ unsigned pack2(float lo, float hi) {
    return (unsigned)bf16_rtne(lo) | ((unsigned)bf16_rtne(hi) << 16);
}

__device__ __forceinline__ void pack_w_body(const float* __restrict__ Wl,
                                            const float* __restrict__ Wr,
                                            unsigned short* __restrict__ Wp, int i) {
    int j = i & 7;
    int l = (i >> 3) & 63;
    int ntile = (i >> 9) & 7;
    int kstep = i >> 12;
    int k = kstep * 32 + (l >> 4) * 8 + j;
    int n = ntile * 16 + (l & 15);
    float v = (k < 128) ? Wl[k * 128 + n] : Wr[(k - 128) * 128 + n];
    Wp[i] = bf16_rtne(v);
}

// Fused dispatch 1: [phase-A bucket scatter | cvt x->bf16 | pack Wp1/Wp2/Wpo].
__global__ __launch_bounds__(256) void bucket_prep_kernel(
        const int* __restrict__ src, const int* __restrict__ dst,
        unsigned int* __restrict__ gtail, unsigned int* __restrict__ gbuf,
        int E, int aBlocks,
        const float* __restrict__ x, unsigned short* __restrict__ xb, int n4, int cvtBlocks,
        const float* __restrict__ Wl0, const float* __restrict__ Wr0,
        unsigned short* __restrict__ Wp1,
        const float* __restrict__ Wl1, const float* __restrict__ Wr1,
        unsigned short* __restrict__ Wp2,
        const float* __restrict__ Wout, unsigned short* __restrict__ Wpo) {
    int b = blockIdx.x;
    if (b < aBlocks) {
        __shared__ unsigned int hist[NBK];
        __shared__ unsigned int pref[NBK + 1];
        __shared__ int baseS[NBK];
        __shared__ unsigned int scat[EPB];
        __shared__ unsigned char scatb[EPB];
        int tid = (int)threadIdx.x;
        int xcd = b & 7;   // XCD heuristic: same (b&7) -> same XCD L2 for segment writes
        hist[tid] = 0u;
        __syncthreads();

        int e0 = b * EPB + tid * 8;
        int dd[8], ss[8], bb[8];
        unsigned rr[8];
        bool vld[8];
        if (e0 + 7 < E) {
            int4 d0 = *(const int4*)(dst + e0);
            int4 d1 = *(const int4*)(dst + e0 + 4);
            int4 s0 = *(const int4*)(src + e0);
            int4 s1 = *(const int4*)(src + e0 + 4);
            dd[0] = d0.x; dd[1] = d0.y; dd[2] = d0.z; dd[3] = d0.w;
            dd[4] = d1.x; dd[5] = d1.y; dd[6] = d1.z; dd[7] = d1.w;
            ss[0] = s0.x; ss[1] = s0.y; ss[2] = s0.z; ss[3] = s0.w;
            ss[4] = s1.x; ss[5] = s1.y; ss[6] = s1.z; ss[7] = s1.w;
#pragma unroll
            for (int u = 0; u < 8; ++u) vld[u] = true;
        } else {
#pragma unroll
            for (int u = 0; u < 8; ++u) {
                int e = e0 + u;
                vld[u] = (e < E);
                dd[u] = vld[u] ? dst[e] : 0;
                ss[u] = vld[u] ? src[e] : 0;
            }
        }
#pragma unroll
        for (int u = 0; u < 8; ++u) {
            bb[u] = dd[u] >> 8;
            rr[u] = vld[u] ? atomicAdd(&hist[bb[u]], 1u) : 0u;
        }
        __syncthreads();
        // exclusive prefix over hist: pref[i] = sum hist[0..i-1] (Hillis-Steele)
        pref[tid + 1] = hist[tid];
        if (tid == 0) pref[0] = 0u;
        __syncthreads();
        for (int off = 1; off < NBK; off <<= 1) {
            unsigned add = (tid + 1 > off) ? pref[tid + 1 - off] : 0u;
            __syncthreads();
            pref[tid + 1] += add;
            __syncthreads();
        }
        // reserve per-(XCD,bucket) segment space: ~196 atomics per block
        {
            unsigned h = hist[tid];
            unsigned gb0 = (h != 0u) ? atomicAdd(&gtail[xcd * NBK + tid], h) : 0u;
            baseS[tid] = (int)((unsigned)(xcd * NBK + tid) * BCAP8 + gb0) - (int)pref[tid];
        }
        __syncthreads();
        // local bucket-sort into LDS
#pragma unroll
        for (int u = 0; u < 8; ++u) {
            if (vld[u]) {
                unsigned idx = pref[bb[u]] + rr[u];
                scat[idx] = ((unsigned)dd[u] << 16) | (unsigned)(ss[u] & 0xFFFF);
                scatb[idx] = (unsigned char)bb[u];
            }
        }
        __syncthreads();
        // dump: contiguous run per bucket -> coalesced-ish, single-XCD lines
        unsigned tot = pref[NBK];
        for (unsigned i = (unsigned)tid; i < tot; i += 256u) {
            int bk = (int)scatb[i];
            int gi = baseS[bk] + (int)i;
            unsigned segBase = (unsigned)(xcd * NBK + bk) * BCAP8;
            if ((unsigned)gi - segBase < BCAP8) gbuf[gi] = scat[i];
        }
    } else if (b < aBlocks + cvtBlocks) {
        int i = (b - aBlocks) * 256 + (int)threadIdx.x;
        if (i < n4) {
            float4 v = ((const float4*)x)[i];
            ushort4 o;
            o.x = bf16_rtne(v.x); o.y = bf16_rtne(v.y);
            o.z = bf16_rtne(v.z); o.w = bf16_rtne(v.w);
            ((ushort4*)xb)[i] = o;
        }
    } else if (b < aBlocks + cvtBlocks + 128) {
        pack_w_body(Wl0, Wr0, Wp1, (b - aBlocks - cvtBlocks) * 256 + (int)threadIdx.x);
    } else if (b < aBlocks + cvtBlocks + 256) {
        pack_w_body(Wl1, Wr1, Wp2, (b - aBlocks - cvtBlocks - 128) * 256 + (int)threadIdx.x);
    } else {
        int i = (b - aBlocks - cvtBlocks - 256) * 256 + (int)threadIdx.x;   // 32 blocks
        int j = i & 7;
        int l = (i >> 3) & 63;
        int nt = (i >> 9) & 3;
        int ks = i >> 11;
        int k = ks * 32 + (l >> 4) * 8 + j;
        int n = nt * 16 + (l & 15);
        Wpo[i] = bf16_rtne(Wout[k * 64 + n]);
    }
}

// Phase B: one block per 256-node bucket, two passes over its 8 XCD segments.
// Pass 1 counts per (node, src-range); per-node prefix -> range-grouped
// placement offsets + packed cnt4 (4 x u8). Pass 2 places via LDS atomics.
// Placement window for range r is [min(pref,CAP), min(pref+c,CAP)) -- the
// gather derives exactly this window from cnt4. Coalesced 32KB tile dump.
__global__ __launch_bounds__(256) void fill_csr_kernel(
        const unsigned int* __restrict__ gtail, const unsigned int* __restrict__ gbuf,
        unsigned int* __restrict__ cnt4, unsigned short* __restrict__ csr, int N) {
    __shared__ unsigned int cntR[256 * NR];       // 4 KB
    __shared__ unsigned int offR[256 * NR];       // 4 KB
    __shared__ unsigned short stage[256 * CAP];   // 32 KB; garbage beyond deg never read
    int b = blockIdx.x;
    int tid = (int)threadIdx.x;
#pragma unroll
    for (int r = 0; r < NR; ++r) cntR[r * 256 + tid] = 0u;
    __syncthreads();
    // pass 1: count per (node, range)
#pragma unroll 1
    for (int xcd = 0; xcd < 8; ++xcd) {
        unsigned nE = gtail[xcd * NBK + b];
        if (nE > BCAP8) nE = BCAP8;
        const unsigned int* g = gbuf + (size_t)(xcd * NBK + b) * BCAP8;
        for (unsigned i = (unsigned)tid; i < nE; i += 256u) {
            unsigned pk = g[i];
            int dl = (int)((pk >> 16) & 255u);
            int rg = (int)((pk & 0xFFFFu) >> RSH);
            atomicAdd(&cntR[dl * NR + rg], 1u);
        }
    }
    __syncthreads();
    // per-node range offsets + packed counts; reset counters for pass 2
    {
        unsigned c0 = cntR[tid * NR + 0], c1 = cntR[tid * NR + 1];
        unsigned c2 = cntR[tid * NR + 2], c3 = cntR[tid * NR + 3];
        offR[tid * NR + 0] = 0u;
        offR[tid * NR + 1] = c0;
        offR[tid * NR + 2] = c0 + c1;
        offR[tid * NR + 3] = c0 + c1 + c2;
        int node = b * 256 + tid;
        if (node < N)
            cnt4[node] = min(c0, 255u) | (min(c1, 255u) << 8) |
                         (min(c2, 255u) << 16) | (min(c3, 255u) << 24);
        cntR[tid * NR + 0] = 0u; cntR[tid * NR + 1] = 0u;
        cntR[tid * NR + 2] = 0u; cntR[tid * NR + 3] = 0u;
    }
    __syncthreads();
    // pass 2: place (src-range-grouped within each node's CAP row)
#pragma unroll 1
    for (int xcd = 0; xcd < 8; ++xcd) {
        unsigned nE = gtail[xcd * NBK + b];
        if (nE > BCAP8) nE = BCAP8;
        const unsigned int* g = gbuf + (size_t)(xcd * NBK + b) * BCAP8;
        for (unsigned i = (unsigned)tid; i < nE; i += 256u) {
            unsigned pk = g[i];
            int dl = (int)((pk >> 16) & 255u);
            int rg = (int)((pk & 0xFFFFu) >> RSH);
            unsigned p = atomicAdd(&cntR[dl * NR + rg], 1u) + offR[dl * NR + rg];
            if (p < CAP) stage[dl * CAP + p] = (unsigned short)(pk & 0xFFFFu);
        }
    }
    __syncthreads();
    const uint4* s4 = (const uint4*)stage;
    uint4* g4 = (uint4*)(csr + (size_t)b * (256 * CAP));
    for (int i = tid; i < (256 * CAP) / 8; i += 256) g4[i] = s4[i];
}

// Paired segment gather: for one src-range, process node A's and node B's
// padded 8-slot batches together -> 16 unconditional clamped row loads in
// flight (R2's MLP regime), uniform control flow, zero-masked pad slots.
// Pad loads duplicate the segment's last row (same cache lines, ~free).
// Lanes 0-7 of the quarter-wave carry A's csr slots, lanes 8-15 B's.
__device__ __forceinline__ void gather_pair(
        const uint4* __restrict__ h4, const unsigned short* __restrict__ csr,
        int ql, int sbA, int lenA, int sbB, int lenB,
        float (&aA)[8], float (&aB)[8]) {
    int nb = (max(lenA, lenB) + 7) >> 3;   // uniform across the quarter-wave
    int myBase = (ql < 8) ? sbA : sbB;
    int myLen  = (ql < 8) ? lenA : lenB;
#pragma unroll 1
    for (int b = 0; b < nb; ++b) {
        int slot = b * 8 + (ql & 7);
        int idx = csr[myBase + min(slot, max(myLen - 1, 0))];
        uint4 vA[8], vB[8];
#pragma unroll
        for (int u = 0; u < 8; ++u) {
            int sA = __shfl(idx, u, 16);
            int sB = __shfl(idx, 8 + u, 16);
            vA[u] = h4[(size_t)sA * 16 + ql];
            vB[u] = h4[(size_t)sB * 16 + ql];
        }
#pragma unroll
        for (int u = 0; u < 8; ++u) {
            bool okA = (b * 8 + u) < lenA;
            bool okB = (b * 8 + u) < lenB;
            unsigned w0 = okA ? vA[u].x : 0u;
            unsigned w1 = okA ? vA[u].y : 0u;
            unsigned w2 = okA ? vA[u].z : 0u;
            unsigned w3 = okA ? vA[u].w : 0u;
            aA[0] += __uint_as_float(w0 << 16);
            aA[1] += __uint_as_float(w0 & 0xFFFF0000u);
            aA[2] += __uint_as_float(w1 << 16);
            aA[3] += __uint_as_float(w1 & 0xFFFF0000u);
            aA[4] += __uint_as_float(w2 << 16);
            aA[5] += __uint_as_float(w2 & 0xFFFF0000u);
            aA[6] += __uint_as_float(w3 << 16);
            aA[7] += __uint_as_float(w3 & 0xFFFF0000u);
            unsigned y0 = okB ? vB[u].x : 0u;
            unsigned y1 = okB ? vB[u].y : 0u;
            unsigned y2 = okB ? vB[u].z : 0u;
            unsigned y3 = okB ? vB[u].w : 0u;
            aB[0] += __uint_as_float(y0 << 16);
            aB[1] += __uint_as_float(y0 & 0xFFFF0000u);
            aB[2] += __uint_as_float(y1 << 16);
            aB[3] += __uint_as_float(y1 & 0xFFFF0000u);
            aB[4] += __uint_as_float(y2 << 16);
            aB[5] += __uint_as_float(y2 & 0xFFFF0000u);
            aB[6] += __uint_as_float(y3 << 16);
            aB[7] += __uint_as_float(y3 & 0xFFFF0000u);
        }
    }
}

// Range-phased per-wave gather+mean into the wave's LDS A-tile.
// r-loop OUTERMOST (L2 phasing, R4-proven FETCH mechanism); within a range,
// the quarter-wave's 4 nodes run as 2 dense pairs (R2-proven MLP regime).
// Accumulators are four NAMED arrays -> all indexing compile-time static.
__device__ __forceinline__ void gather_mean_lds(
        const uint4* __restrict__ h4,          // bf16 table, one row = 16 uint4
        const unsigned* __restrict__ cnt4,     // packed per-range degrees (4 x u8)
        const unsigned short* __restrict__ csr, unsigned short* __restrict__ sAw,
        int m0, int lane, int N) {
    int qw = lane >> 4;      // quarter-wave 0..3
    int ql = lane & 15;
    float a0[8], a1[8], a2[8], a3[8];
#pragma unroll
    for (int u = 0; u < 8; ++u) { a0[u] = 0.f; a1[u] = 0.f; a2[u] = 0.f; a3[u] = 0.f; }
    unsigned pc[4];
    int s0[4], st[4];
#pragma unroll
    for (int i = 0; i < 4; ++i) {
        int node = m0 + qw * 4 + i;
        pc[i] = (node < N) ? cnt4[node] : 0u;
        s0[i] = node * CAP;
        st[i] = 0;
    }
#pragma unroll 1
    for (int r = 0; r < NR; ++r) {
        int len[4], sb[4];
#pragma unroll
        for (int i = 0; i < 4; ++i) {
            int c = (int)((pc[i] >> (8 * r)) & 255u);
            int stc = min(st[i], CAP);
            len[i] = min(c, CAP - stc);
            sb[i] = s0[i] + stc;
            st[i] += c;
        }
        gather_pair(h4, csr, ql, sb[0], len[0], sb[1], len[1], a0, a1);
        gather_pair(h4, csr, ql, sb[2], len[2], sb[3], len[3], a2, a3);
    }
#pragma unroll
    for (int i = 0; i < 4; ++i) {
        unsigned c = pc[i];
        int tot = (int)((c & 255u) + ((c >> 8) & 255u) +
                        ((c >> 16) & 255u) + ((c >> 24) & 255u));
        int deg = min(tot, CAP);
        float inv = 1.0f / (float)max(deg, 1);
        const float* ai = (i == 0) ? a0 : (i == 1) ? a1 : (i == 2) ? a2 : a3;
        int nl = qw * 4 + i;
        uint4 o;
        o.x = pack2(ai[0] * inv, ai[1] * inv);
        o.y = pack2(ai[2] * inv, ai[3] * inv);
        o.z = pack2(ai[4] * inv, ai[5] * inv);
        o.w = pack2(ai[6] * inv, ai[7] * inv);
        *(uint4*)(sAw + nl * ASTR + ql * 8) = o;   // 272B row -> bank-floor reads
    }
}

// MFMA core: wave computes 16 nodes x 128 cols, K=256 ([aggLDS|rootGlobal]).
__device__ __forceinline__ void mfma_dual_gemm_lds(
        const unsigned short* __restrict__ sAw, const unsigned short* __restrict__ rootb,
        const unsigned short* __restrict__ Wp, int rowc, int quad, int c, int lane,
        f32x4 acc[8]) {
#pragma unroll
    for (int t = 0; t < 8; ++t) acc[t] = (f32x4){0.f, 0.f, 0.f, 0.f};
    for (int ks = 0; ks < 8; ++ks) {
        bf16x8 a;
        if (ks < 4) a = *(const bf16x8*)(sAw + c * ASTR + ks * 32 + quad * 8);
        else        a = *(const bf16x8*)(rootb + (size_t)rowc * 128 + (ks & 3) * 32 + quad * 8);
#pragma unroll
        for (int t = 0; t < 8; ++t) {
            bf16x8 bf = *(const bf16x8*)(Wp + ((size_t)(ks * 8 + t) * 64 + lane) * 8);
            acc[t] = __builtin_amdgcn_mfma_f32_16x16x32_bf16(a, bf, acc[t], 0, 0, 0);
        }
    }
}

// Layer 1: h0 = relu(mean_agg(x)@Wl + x@Wr + b) -> bf16 store.
// Gather, GEMM, and the h0 repack all stay on the wave's own LDS tile:
// no barriers (DS ops wave-ordered). h0 stored as coalesced 256B rows.
__global__ __launch_bounds__(256) void fused_l1_kernel(
        const unsigned short* __restrict__ hb, const unsigned* __restrict__ cnt4,
        const unsigned short* __restrict__ csr, const unsigned short* __restrict__ Wp,
        const float* __restrict__ b, unsigned short* __restrict__ houtb, int N) {
    __shared__ unsigned short sA[4][16 * ASTR];   // 17.4 KB
    int lane = threadIdx.x & 63;
    int wv = threadIdx.x >> 6;
    int m0 = blockIdx.x * 64 + wv * 16;
    gather_mean_lds((const uint4*)hb, cnt4, csr, &sA[wv][0], m0, lane, N);
    int quad = lane >> 4;
    int c = lane & 15;
    int rowc = min(m0 + c, N - 1);
    f32x4 acc[8];
    mfma_dual_gemm_lds(&sA[wv][0], hb, Wp, rowc, quad, c, lane, acc);
    // relu+bias -> sA (overwrites A-tile; wave-private, DS wave-ordered)
#pragma unroll
    for (int t = 0; t < 8; ++t) {
        int col = t * 16 + c;
        float bias = b[col];
#pragma unroll
        for (int r = 0; r < 4; ++r) {
            sA[wv][(quad * 4 + r) * ASTR + col] = bf16_rtne(fmaxf(acc[t][r] + bias, 0.f));
        }
    }
    // coalesced store: quarter-wave ql covers 16B -> 256B per row per instr
    {
        int qw = lane >> 4, ql = lane & 15;
#pragma unroll
        for (int i = 0; i < 4; ++i) {
            int nl = qw * 4 + i;
            int node = m0 + nl;
            if (node < N) {
                uint4 row = *(const uint4*)(&sA[wv][nl * ASTR + ql * 8]);
                *(uint4*)(houtb + (size_t)node * 128 + ql * 8) = row;
            }
        }
    }
}

// Layer 2 + out-projection + softmax. h1 tile staged back into the same LDS
// A-tile (stride 136 -> conflict-floor reads in the out-proj too). No barriers.
__global__ __launch_bounds__(256) void fused_l2_kernel(
        const unsigned short* __restrict__ hb, const unsigned* __restrict__ cnt4,
        const unsigned short* __restrict__ csr, const unsigned short* __restrict__ Wp,
        const float* __restrict__ b,
        const unsigned short* __restrict__ Wpo, const float* __restrict__ bout,
        float* __restrict__ out, int N) {
    __shared__ unsigned short sA[4][16 * ASTR];   // 17.4 KB, reused for h1 tile
    int lane = threadIdx.x & 63;
    int wv = threadIdx.x >> 6;
    int m0 = blockIdx.x * 64 + wv * 16;
    gather_mean_lds((const uint4*)hb, cnt4, csr, &sA[wv][0], m0, lane, N);
    int quad = lane >> 4;
    int c = lane & 15;
    int rowc = min(m0 + c, N - 1);
    f32x4 acc[8];
    mfma_dual_gemm_lds(&sA[wv][0], hb, Wp, rowc, quad, c, lane, acc);
    // relu -> h1 tile in LDS (wave-private; DS ops are wave-ordered, no barrier)
#pragma unroll
    for (int t = 0; t < 8; ++t) {
        int col = t * 16 + c;
        float bias = b[col];
#pragma unroll
        for (int r = 0; r < 4; ++r) {
            sA[wv][(quad * 4 + r) * ASTR + col] = bf16_rtne(fmaxf(acc[t][r] + bias, 0.f));
        }
    }

    // out = h1 @ Wout : K=128 (4 ksteps), N=64 (4 ntiles) -> 16 MFMAs.
    f32x4 acc2[4];
#pragma unroll
    for (int nt = 0; nt < 4; ++nt) acc2[nt] = (f32x4){0.f, 0.f, 0.f, 0.f};
#pragma unroll
    for (int ks = 0; ks < 4; ++ks) {
        bf16x8 a = *(const bf16x8*)&sA[wv][c * ASTR + ks * 32 + quad * 8];
#pragma unroll
        for (int nt = 0; nt < 4; ++nt) {
            bf16x8 bf = *(const bf16x8*)(Wpo + ((size_t)(ks * 4 + nt) * 64 + lane) * 8);
            acc2[nt] = __builtin_amdgcn_mfma_f32_16x16x32_bf16(a, bf, acc2[nt], 0, 0, 0);
        }
    }

    // softmax: row m=quad*4+r lives in a 16-lane group x 4 regs (nt).
    float bo[4];
#pragma unroll
    for (int nt = 0; nt < 4; ++nt) bo[nt] = bout[nt * 16 + c];
#pragma unroll
    for (int r = 0; r < 4; ++r) {
        float v[4];
#pragma unroll
        for (int nt = 0; nt < 4; ++nt) v[nt] = acc2[nt][r] + bo[nt];
        float m = fmaxf(fmaxf(v[0], v[1]), fmaxf(v[2], v[3]));
#pragma unroll
        for (int ofs = 1; ofs < 16; ofs <<= 1) m = fmaxf(m, __shfl_xor(m, ofs, 64));
        float e[4];
        float s = 0.f;
#pragma unroll
        for (int nt = 0; nt < 4; ++nt) { e[nt] = __expf(v[nt] - m); s += e[nt]; }
#pragma unroll
        for (int ofs = 1; ofs < 16; ofs <<= 1) s += __shfl_xor(s, ofs, 64);
        float inv = 1.0f / s;
        int node = m0 + quad * 4 + r;
        if (node < N) {
#pragma unroll
            for (int nt = 0; nt < 4; ++nt)
                out[(size_t)node * 64 + nt * 16 + c] = e[nt] * inv;
        }
    }
}

extern "C" void kernel_launch(void* const* d_in, const int* in_sizes, int n_in,
                              void* d_out, int out_size, void* d_ws, size_t ws_size,
                              hipStream_t stream) {
    const float* x    = (const float*)d_in[0];
    const int*   ei   = (const int*)d_in[1];
    const float* Wl0  = (const float*)d_in[2];
    const float* Wr0  = (const float*)d_in[3];
    const float* b0   = (const float*)d_in[4];
    const float* Wl1  = (const float*)d_in[5];
    const float* Wr1  = (const float*)d_in[6];
    const float* b1   = (const float*)d_in[7];
    const float* Wout = (const float*)d_in[8];
    const float* bout = (const float*)d_in[9];

    int N = in_sizes[0] / 128;
    int E = in_sizes[1] / 2;
    const int* src = ei;
    const int* dst = ei + E;
    int nb = (N + 255) >> 8;             // node buckets (256 nodes each)

    char* p = (char*)d_ws;
    auto alloc = [&](size_t bytes) -> char* {
        char* r = p;
        p += (bytes + 255) & ~(size_t)255;
        return r;
    };
    unsigned int*   gtail = (unsigned int*)alloc((size_t)8 * NBK * 4);
    unsigned int*   gbuf  = (unsigned int*)alloc((size_t)8 * NBK * BCAP8 * 4);
    unsigned int*   cnt4  = (unsigned int*)alloc((size_t)N * 4);
    unsigned short* csr   = (unsigned short*)alloc((size_t)nb * 256 * CAP * 2);
    unsigned short* xb    = (unsigned short*)alloc((size_t)N * 128 * 2);
    unsigned short* h0b   = (unsigned short*)alloc((size_t)N * 128 * 2);
    unsigned short* Wp1   = (unsigned short*)alloc((size_t)32768 * 2);
    unsigned short* Wp2   = (unsigned short*)alloc((size_t)32768 * 2);
    unsigned short* Wpo   = (unsigned short*)alloc((size_t)8192 * 2);

    hipMemsetAsync(gtail, 0, (size_t)8 * NBK * 4, stream);

    int n4 = N * 128 / 4;
    int cvtBlocks = (n4 + 255) / 256;
    int aBlocks = (E + EPB - 1) / EPB;
    bucket_prep_kernel<<<aBlocks + cvtBlocks + 256 + 32, 256, 0, stream>>>(
        src, dst, gtail, gbuf, E, aBlocks,
        x, xb, n4, cvtBlocks, Wl0, Wr0, Wp1, Wl1, Wr1, Wp2, Wout, Wpo);

    fill_csr_kernel<<<nb, 256, 0, stream>>>(gtail, gbuf, cnt4, csr, N);

    int gb = (N + 63) / 64;          // fused: 64 nodes/block (4 waves x 16)
    fused_l1_kernel<<<gb, 256, 0, stream>>>(xb, cnt4, csr, Wp1, b0, h0b, N);
    fused_l2_kernel<<<gb, 256, 0, stream>>>(h0b, cnt4, csr, Wp2, b1,
                                            Wpo, bout, (float*)d_out, N);
}

// Round 7
// 187.105 us; speedup vs baseline: 1.2377x; 1.2377x over previous
//
#include <hip/hip_runtime.h>

// GraphSAGE: 2x SAGEConv(mean) + Linear + softmax.
// Pipeline (4 kernel dispatches, no memset):
//   bucket_prep (phase-A LDS bucket-sort -> COALESCED SLAB DUMP | cvt x->bf16
//                | pack W frags)
//   -> fill_csr (per-bucket: walk slabs, read runs, LDS-atomic place, dump)
//   -> fused_l1 (gather-mean into LDS + dual MFMA GEMM + relu -> h0 bf16)
//   -> fused_l2 (gather-mean + dual GEMM + relu -> LDS + out-proj + softmax).
//
// This round: SLAB-DUMP CSR BUILD (gather untouched = R5's proven form).
// R6 post-mortem: paired-range gather cut FETCH to 73MB but ~2x'd issued
// loads (pad-to-8 on ~4-edge segments) and dropped occupancy (92 VGPR) ->
// 66.9us. 0-for-3 on gather phasing; R2/R5 dense-clamped gather restored.
// New target: prep's dump was 800k scattered 4B stores (~40B runs) into
// per-(XCD,bucket) segments + 100k hot global atomics + a memset dispatch.
// Now: each phase-A block dumps its 2048 LDS-sorted edges CONTIGUOUSLY into
// its own 8KB slab (coalesced burst) + one packed u32 row of per-bucket
// (start | end<<16) offsets. No global atomics, no gtail, no memset.
// fill_csr block bk walks all slabs, reads its ~10-edge runs (scattered 40B
// READS -- latency-tolerant, unlike RMW writes), places via LDS atomics
// directly into the stage (1 pass, 33KB LDS -> 4 blocks/CU), dumps 32KB
// coalesced + capped cnt. Per-node neighbor order is arrival-nondeterministic
// (same class as the R0 atomic build that passed; f32 sum within tol).
//
// Dual GEMM as one K=256 MFMA GEMM: A_cat=[agg|root] bf16, W_cat=[Wl;Wr] packed.
// mfma_f32_16x16x32_bf16: A[m=lane&15][k=(lane>>4)*8+j]; B[k][n=lane&15];
// C: col=lane&15, row=(lane>>4)*4+reg (m89/m91-verified layouts).
// Zero barriers in the fused kernels (wave-private LDS tiles, DS wave-ordered).

#define CAP 64
#define NBK 256      // bucket table stride (max buckets; N<=65536)
#define EPB 2048     // edges per phase-A block (8 per thread) = one slab
#define ASTR 136     // LDS A-tile row stride in ushorts (272B = 17x16B)

typedef __attribute__((ext_vector_type(8))) short bf16x8;
typedef __attribute__((ext_vector_type(4))) float f32x4;

__device__ __forceinline__ unsigned short bf16_rtne(float f) {
    unsigned u = __float_as_uint(f);
    u += 0x7FFFu + ((u >> 16) & 1u);
    return (unsigned short)(u >> 16);
}

__device__ __forceinline__ unsigned pack2(float lo, float hi) {
    return (unsigned)bf16_rtne(lo) | ((unsigned)bf16_rtne(hi) << 16);
}

__device__ __forceinline__ void pack_w_body(const float* __restrict__ Wl,
                                            const float* __restrict__ Wr,
                                            unsigned short* __restrict__ Wp, int i) {
    int j = i & 7;
    int l = (i >> 3) & 63;
    int ntile = (i >> 9) & 7;
    int kstep = i >> 12;
    int k = kstep * 32 + (l >> 4) * 8 + j;
    int n = ntile * 16 + (l & 15);
    float v = (k < 128) ? Wl[k * 128 + n] : Wr[(k - 128) * 128 + n];
    Wp[i] = bf16_rtne(v);
}

// Fused dispatch 1: [phase-A bucket-sort + slab dump | cvt x->bf16 | pack W].
__global__ __launch_bounds__(256) void bucket_prep_kernel(
        const int* __restrict__ src, const int* __restrict__ dst,
        unsigned int* __restrict__ pref2, unsigned int* __restrict__ gbuf,
        int E, int aBlocks,
        const float* __restrict__ x, unsigned short* __restrict__ xb, int n4, int cvtBlocks,
        const float* __restrict__ Wl0, const float* __restrict__ Wr0,
        unsigned short* __restrict__ Wp1,
        const float* __restrict__ Wl1, const float* __restrict__ Wr1,
        unsigned short* __restrict__ Wp2,
        const float* __restrict__ Wout, unsigned short* __restrict__ Wpo) {
    int b = blockIdx.x;
    if (b < aBlocks) {
        __shared__ unsigned int hist[NBK];
        __shared__ unsigned int pref[NBK + 1];
        __shared__ unsigned int scat[EPB];      // 8 KB slab image
        int tid = (int)threadIdx.x;
        hist[tid] = 0u;
        __syncthreads();

        int e0 = b * EPB + tid * 8;
        int dd[8], ss[8], bb[8];
        unsigned rr[8];
        bool vld[8];
        if (e0 + 7 < E) {
            int4 d0 = *(const int4*)(dst + e0);
            int4 d1 = *(const int4*)(dst + e0 + 4);
            int4 s0 = *(const int4*)(src + e0);
            int4 s1 = *(const int4*)(src + e0 + 4);
            dd[0] = d0.x; dd[1] = d0.y; dd[2] = d0.z; dd[3] = d0.w;
            dd[4] = d1.x; dd[5] = d1.y; dd[6] = d1.z; dd[7] = d1.w;
            ss[0] = s0.x; ss[1] = s0.y; ss[2] = s0.z; ss[3] = s0.w;
            ss[4] = s1.x; ss[5] = s1.y; ss[6] = s1.z; ss[7] = s1.w;
#pragma unroll
            for (int u = 0; u < 8; ++u) vld[u] = true;
        } else {
#pragma unroll
            for (int u = 0; u < 8; ++u) {
                int e = e0 + u;
                vld[u] = (e < E);
                dd[u] = vld[u] ? dst[e] : 0;
                ss[u] = vld[u] ? src[e] : 0;
            }
        }
#pragma unroll
        for (int u = 0; u < 8; ++u) {
            bb[u] = dd[u] >> 8;
            rr[u] = vld[u] ? atomicAdd(&hist[bb[u]], 1u) : 0u;
        }
        __syncthreads();
        // exclusive prefix over hist: pref[i] = sum hist[0..i-1] (Hillis-Steele)
        pref[tid + 1] = hist[tid];
        if (tid == 0) pref[0] = 0u;
        __syncthreads();
        for (int off = 1; off < NBK; off <<= 1) {
            unsigned add = (tid + 1 > off) ? pref[tid + 1 - off] : 0u;
            __syncthreads();
            pref[tid + 1] += add;
            __syncthreads();
        }
        // local bucket-sort into the slab image
#pragma unroll
        for (int u = 0; u < 8; ++u) {
            if (vld[u]) {
                unsigned idx = pref[bb[u]] + rr[u];
                scat[idx] = ((unsigned)dd[u] << 16) | (unsigned)(ss[u] & 0xFFFF);
            }
        }
        __syncthreads();
        // coalesced slab dump: full 8KB burst (tail garbage never read --
        // pref row bounds every bucket's run)
        {
            uint4* g4 = (uint4*)(gbuf + (size_t)b * EPB);
            const uint4* s4 = (const uint4*)scat;
            for (int i = tid; i < EPB / 4; i += 256) g4[i] = s4[i];
        }
        // packed per-bucket offsets: (start | end<<16), both <= 2048 (fit u16)
        pref2[(size_t)b * NBK + tid] = (pref[tid] & 0xFFFFu) | (pref[tid + 1] << 16);
    } else if (b < aBlocks + cvtBlocks) {
        int i = (b - aBlocks) * 256 + (int)threadIdx.x;
        if (i < n4) {
            float4 v = ((const float4*)x)[i];
            ushort4 o;
            o.x = bf16_rtne(v.x); o.y = bf16_rtne(v.y);
            o.z = bf16_rtne(v.z); o.w = bf16_rtne(v.w);
            ((ushort4*)xb)[i] = o;
        }
    } else if (b < aBlocks + cvtBlocks + 128) {
        pack_w_body(Wl0, Wr0, Wp1, (b - aBlocks - cvtBlocks) * 256 + (int)threadIdx.x);
    } else if (b < aBlocks + cvtBlocks + 256) {
        pack_w_body(Wl1, Wr1, Wp2, (b - aBlocks - cvtBlocks - 128) * 256 + (int)threadIdx.x);
    } else {
        int i = (b - aBlocks - cvtBlocks - 256) * 256 + (int)threadIdx.x;   // 32 blocks
        int j = i & 7;
        int l = (i >> 3) & 63;
        int nt = (i >> 9) & 3;
        int ks = i >> 11;
        int k = ks * 32 + (l >> 4) * 8 + j;
        int n = nt * 16 + (l & 15);
        Wpo[i] = bf16_rtne(Wout[k * 64 + n]);
    }
}

// One block per 256-node bucket: walk all slabs, read this bucket's run from
// each (scattered ~40B reads; latency-tolerant), place via LDS atomics into
// the stage, dump 32KB coalesced + capped cnt. No global atomics, one pass.
__global__ __launch_bounds__(256) void fill_csr_kernel(
        const unsigned int* __restrict__ pref2, const unsigned int* __restrict__ gbuf,
        int* __restrict__ cnt, unsigned short* __restrict__ csr, int N, int aBlocks) {
    __shared__ unsigned int cntL[256];            // 1 KB
    __shared__ unsigned short stage[256 * CAP];   // 32 KB; garbage beyond deg never read
    int bk = blockIdx.x;
    int tid = (int)threadIdx.x;
    cntL[tid] = 0u;
    __syncthreads();
    for (int b = tid; b < aBlocks; b += 256) {
        unsigned pr = pref2[(size_t)b * NBK + bk];
        unsigned st = pr & 0xFFFFu;
        unsigned en = pr >> 16;
        const unsigned int* slab = gbuf + (size_t)b * EPB;
        for (unsigned i = st; i < en; ++i) {
            unsigned pk = slab[i];
            int dl = (int)((pk >> 16) & 255u);
            unsigned p = atomicAdd(&cntL[dl], 1u);
            if (p < CAP) stage[dl * CAP + p] = (unsigned short)(pk & 0xFFFFu);
        }
    }
    __syncthreads();
    const uint4* s4 = (const uint4*)stage;
    uint4* g4 = (uint4*)(csr + (size_t)bk * (256 * CAP));
    for (int i = tid; i < (256 * CAP) / 8; i += 256) g4[i] = s4[i];
    int node = bk * 256 + tid;
    if (node < N) cnt[node] = min((int)cntL[tid], CAP);
}

// Per-wave gather+mean into the wave's LDS A-tile (R2/R5 structure, verbatim:
// the MLP-efficient regime; 3x phasing attempts all regressed). Quarter-wave
// (16 lanes x uint4 = one 256B row per instr) per node, 8 rows in flight,
// clamped dense batches over the full neighbor list.
__device__ __forceinline__ void gather_mean_lds(
        const uint4* __restrict__ h4,          // bf16 table, one row = 16 uint4
        const int* __restrict__ cnt,
        const unsigned short* __restrict__ csr, unsigned short* __restrict__ sAw,
        int m0, int lane, int N) {
    int qw = lane >> 4;      // quarter-wave 0..3
    int ql = lane & 15;
#pragma unroll 1
    for (int i = 0; i < 4; ++i) {
        int nl = qw * 4 + i;
        int node = m0 + nl;
        int deg = (node < N) ? min(cnt[node], CAP) : 0;
        int s0 = node * CAP;
        int s1 = s0 + deg;
        float a[8];
#pragma unroll
        for (int u = 0; u < 8; ++u) a[u] = 0.f;
        for (int base = 0; base < deg; base += 16) {
            int nc = min(16, deg - base);
            int e = min(s0 + base + ql, s1 - 1);
            int idx = csr[e];
            for (int j = 0; j < nc; j += 8) {
                uint4 v[8];
#pragma unroll
                for (int u = 0; u < 8; ++u) {
                    int sidx = __shfl(idx, j + u, 16);
                    v[u] = h4[(size_t)sidx * 16 + ql];
                }
#pragma unroll
                for (int u = 0; u < 8; ++u) {
                    bool ok = (j + u < nc);
                    unsigned w0 = ok ? v[u].x : 0u;
                    unsigned w1 = ok ? v[u].y : 0u;
                    unsigned w2 = ok ? v[u].z : 0u;
                    unsigned w3 = ok ? v[u].w : 0u;
                    a[0] += __uint_as_float(w0 << 16);
                    a[1] += __uint_as_float(w0 & 0xFFFF0000u);
                    a[2] += __uint_as_float(w1 << 16);
                    a[3] += __uint_as_float(w1 & 0xFFFF0000u);
                    a[4] += __uint_as_float(w2 << 16);
                    a[5] += __uint_as_float(w2 & 0xFFFF0000u);
                    a[6] += __uint_as_float(w3 << 16);
                    a[7] += __uint_as_float(w3 & 0xFFFF0000u);
                }
            }
        }
        float inv = 1.0f / (float)max(deg, 1);
        uint4 o;
        o.x = pack2(a[0] * inv, a[1] * inv);
        o.y = pack2(a[2] * inv, a[3] * inv);
        o.z = pack2(a[4] * inv, a[5] * inv);
        o.w = pack2(a[6] * inv, a[7] * inv);
        *(uint4*)(sAw + nl * ASTR + ql * 8) = o;   // 272B row -> bank-floor reads
    }
}

// MFMA core: wave computes 16 nodes x 128 cols, K=256 ([aggLDS|rootGlobal]).
__device__ __forceinline__ void mfma_dual_gemm_lds(
        const unsigned short* __restrict__ sAw, const unsigned short* __restrict__ rootb,
        const unsigned short* __restrict__ Wp, int rowc, int quad, int c, int lane,
        f32x4 acc[8]) {
#pragma unroll
    for (int t = 0; t < 8; ++t) acc[t] = (f32x4){0.f, 0.f, 0.f, 0.f};
    for (int ks = 0; ks < 8; ++ks) {
        bf16x8 a;
        if (ks < 4) a = *(const bf16x8*)(sAw + c * ASTR + ks * 32 + quad * 8);
        else        a = *(const bf16x8*)(rootb + (size_t)rowc * 128 + (ks & 3) * 32 + quad * 8);
#pragma unroll
        for (int t = 0; t < 8; ++t) {
            bf16x8 bf = *(const bf16x8*)(Wp + ((size_t)(ks * 8 + t) * 64 + lane) * 8);
            acc[t] = __builtin_amdgcn_mfma_f32_16x16x32_bf16(a, bf, acc[t], 0, 0, 0);
        }
    }
}

// Layer 1: h0 = relu(mean_agg(x)@Wl + x@Wr + b) -> bf16 store.
// Gather, GEMM, and the h0 repack all stay on the wave's own LDS tile:
// no barriers (DS ops wave-ordered). h0 stored as coalesced 256B rows.
__global__ __launch_bounds__(256) void fused_l1_kernel(
        const unsigned short* __restrict__ hb, const int* __restrict__ cnt,
        const unsigned short* __restrict__ csr, const unsigned short* __restrict__ Wp,
        const float* __restrict__ b, unsigned short* __restrict__ houtb, int N) {
    __shared__ unsigned short sA[4][16 * ASTR];   // 17.4 KB
    int lane = threadIdx.x & 63;
    int wv = threadIdx.x >> 6;
    int m0 = blockIdx.x * 64 + wv * 16;
    gather_mean_lds((const uint4*)hb, cnt, csr, &sA[wv][0], m0, lane, N);
    int quad = lane >> 4;
    int c = lane & 15;
    int rowc = min(m0 + c, N - 1);
    f32x4 acc[8];
    mfma_dual_gemm_lds(&sA[wv][0], hb, Wp, rowc, quad, c, lane, acc);
    // relu+bias -> sA (overwrites A-tile; wave-private, DS wave-ordered)
#pragma unroll
    for (int t = 0; t < 8; ++t) {
        int col = t * 16 + c;
        float bias = b[col];
#pragma unroll
        for (int r = 0; r < 4; ++r) {
            sA[wv][(quad * 4 + r) * ASTR + col] = bf16_rtne(fmaxf(acc[t][r] + bias, 0.f));
        }
    }
    // coalesced store: quarter-wave ql covers 16B -> 256B per row per instr
    {
        int qw = lane >> 4, ql = lane & 15;
#pragma unroll
        for (int i = 0; i < 4; ++i) {
            int nl = qw * 4 + i;
            int node = m0 + nl;
            if (node < N) {
                uint4 row = *(const uint4*)(&sA[wv][nl * ASTR + ql * 8]);
                *(uint4*)(houtb + (size_t)node * 128 + ql * 8) = row;
            }
        }
    }
}

// Layer 2 + out-projection + softmax. h1 tile staged back into the same LDS
// A-tile (stride 136 -> conflict-floor reads in the out-proj too). No barriers.
__global__ __launch_bounds__(256) void fused_l2_kernel(
        const unsigned short* __restrict__ hb, const int* __restrict__ cnt,
        const unsigned short* __restrict__ csr, const unsigned short* __restrict__ Wp,
        const float* __restrict__ b,
        const unsigned short* __restrict__ Wpo, const float* __restrict__ bout,
        float* __restrict__ out, int N) {
    __shared__ unsigned short sA[4][16 * ASTR];   // 17.4 KB, reused for h1 tile
    int lane = threadIdx.x & 63;
    int wv = threadIdx.x >> 6;
    int m0 = blockIdx.x * 64 + wv * 16;
    gather_mean_lds((const uint4*)hb, cnt, csr, &sA[wv][0], m0, lane, N);
    int quad = lane >> 4;
    int c = lane & 15;
    int rowc = min(m0 + c, N - 1);
    f32x4 acc[8];
    mfma_dual_gemm_lds(&sA[wv][0], hb, Wp, rowc, quad, c, lane, acc);
    // relu -> h1 tile in LDS (wave-private; DS ops are wave-ordered, no barrier)
#pragma unroll
    for (int t = 0; t < 8; ++t) {
        int col = t * 16 + c;
        float bias = b[col];
#pragma unroll
        for (int r = 0; r < 4; ++r) {
            sA[wv][(quad * 4 + r) * ASTR + col] = bf16_rtne(fmaxf(acc[t][r] + bias, 0.f));
        }
    }

    // out = h1 @ Wout : K=128 (4 ksteps), N=64 (4 ntiles) -> 16 MFMAs.
    f32x4 acc2[4];
#pragma unroll
    for (int nt = 0; nt < 4; ++nt) acc2[nt] = (f32x4){0.f, 0.f, 0.f, 0.f};
#pragma unroll
    for (int ks = 0; ks < 4; ++ks) {
        bf16x8 a = *(const bf16x8*)&sA[wv][c * ASTR + ks * 32 + quad * 8];
#pragma unroll
        for (int nt = 0; nt < 4; ++nt) {
            bf16x8 bf = *(const bf16x8*)(Wpo + ((size_t)(ks * 4 + nt) * 64 + lane) * 8);
            acc2[nt] = __builtin_amdgcn_mfma_f32_16x16x32_bf16(a, bf, acc2[nt], 0, 0, 0);
        }
    }

    // softmax: row m=quad*4+r lives in a 16-lane group x 4 regs (nt).
    float bo[4];
#pragma unroll
    for (int nt = 0; nt < 4; ++nt) bo[nt] = bout[nt * 16 + c];
#pragma unroll
    for (int r = 0; r < 4; ++r) {
        float v[4];
#pragma unroll
        for (int nt = 0; nt < 4; ++nt) v[nt] = acc2[nt][r] + bo[nt];
        float m = fmaxf(fmaxf(v[0], v[1]), fmaxf(v[2], v[3]));
#pragma unroll
        for (int ofs = 1; ofs < 16; ofs <<= 1) m = fmaxf(m, __shfl_xor(m, ofs, 64));
        float e[4];
        float s = 0.f;
#pragma unroll
        for (int nt = 0; nt < 4; ++nt) { e[nt] = __expf(v[nt] - m); s += e[nt]; }
#pragma unroll
        for (int ofs = 1; ofs < 16; ofs <<= 1) s += __shfl_xor(s, ofs, 64);
        float inv = 1.0f / s;
        int node = m0 + quad * 4 + r;
        if (node < N) {
#pragma unroll
            for (int nt = 0; nt < 4; ++nt)
                out[(size_t)node * 64 + nt * 16 + c] = e[nt] * inv;
        }
    }
}

extern "C" void kernel_launch(void* const* d_in, const int* in_sizes, int n_in,
                              void* d_out, int out_size, void* d_ws, size_t ws_size,
                              hipStream_t stream) {
    const float* x    = (const float*)d_in[0];
    const int*   ei   = (const int*)d_in[1];
    const float* Wl0  = (const float*)d_in[2];
    const float* Wr0  = (const float*)d_in[3];
    const float* b0   = (const float*)d_in[4];
    const float* Wl1  = (const float*)d_in[5];
    const float* Wr1  = (const float*)d_in[6];
    const float* b1   = (const float*)d_in[7];
    const float* Wout = (const float*)d_in[8];
    const float* bout = (const float*)d_in[9];

    int N = in_sizes[0] / 128;
    int E = in_sizes[1] / 2;
    const int* src = ei;
    const int* dst = ei + E;
    int nb = (N + 255) >> 8;             // node buckets (256 nodes each)
    int aBlocks = (E + EPB - 1) / EPB;   // phase-A blocks = slabs

    char* p = (char*)d_ws;
    auto alloc = [&](size_t bytes) -> char* {
        char* r = p;
        p += (bytes + 255) & ~(size_t)255;
        return r;
    };
    unsigned int*   pref2 = (unsigned int*)alloc((size_t)aBlocks * NBK * 4);
    unsigned int*   gbuf  = (unsigned int*)alloc((size_t)aBlocks * EPB * 4);
    int*            cnt   = (int*)alloc((size_t)N * 4);
    unsigned short* csr   = (unsigned short*)alloc((size_t)nb * 256 * CAP * 2);
    unsigned short* xb    = (unsigned short*)alloc((size_t)N * 128 * 2);
    unsigned short* h0b   = (unsigned short*)alloc((size_t)N * 128 * 2);
    unsigned short* Wp1   = (unsigned short*)alloc((size_t)32768 * 2);
    unsigned short* Wp2   = (unsigned short*)alloc((size_t)32768 * 2);
    unsigned short* Wpo   = (unsigned short*)alloc((size_t)8192 * 2);

    int n4 = N * 128 / 4;
    int cvtBlocks = (n4 + 255) / 256;
    bucket_prep_kernel<<<aBlocks + cvtBlocks + 256 + 32, 256, 0, stream>>>(
        src, dst, pref2, gbuf, E, aBlocks,
        x, xb, n4, cvtBlocks, Wl0, Wr0, Wp1, Wl1, Wr1, Wp2, Wout, Wpo);

    fill_csr_kernel<<<nb, 256, 0, stream>>>(pref2, gbuf, cnt, csr, N, aBlocks);

    int gb = (N + 63) / 64;          // fused: 64 nodes/block (4 waves x 16)
    fused_l1_kernel<<<gb, 256, 0, stream>>>(xb, cnt, csr, Wp1, b0, h0b, N);
    fused_l2_kernel<<<gb, 256, 0, stream>>>(h0b, cnt, csr, Wp2, b1,
                                            Wpo, bout, (float*)d_out, N);
}

// Round 8
// 184.128 us; speedup vs baseline: 1.2577x; 1.0162x over previous
//
#include <hip/hip_runtime.h>

// GraphSAGE: 2x SAGEConv(mean) + Linear + softmax.
// Pipeline (4 kernel dispatches, no memset):
//   bucket_prep (phase-A LDS bucket-sort -> coalesced slab dump | cvt x->bf16
//                | pack W frags)
//   -> fill_csr (per-bucket: walk slabs, read runs, LDS-atomic place, dump)
//   -> fused_l1 (CO-GATHERED tile + half-split dual MFMA GEMM + relu -> h0)
//   -> fused_l2 (same + out-proj + softmax).
//
// This round: 2-WAVE CO-GATHER PER 16-NODE TILE (TLP doubling).
// Evidence: wall pinned at 187us across 3 different CSR builds -> fused
// kernels are the limiter. Their grid (one wave per 16 nodes, N/16 = 3125
// waves = 12.2 waves/CU) caps occupancy at ~38% of the 32-wave capacity --
// invariant to block reshaping while 1 wave owns 16 nodes. Gather runs at
// ~3.3TB/s effective (vs 6.3 streaming) with VGPR/LDS headroom -> latency-
// bound at half TLP. Fix: block = 128 thr (2 waves) per tile; each wave
// gathers 8 rows (inner loop = R2/R5 verbatim: dense clamped 256B uint4
// loads, 8 in flight/quarter-wave) into a block-shared LDS tile; GEMM split
// by column halves (wave w -> ntiles w*4..w*4+3). Grid 3125 blocks ->
// 24.4 waves/CU. 3 barriers/kernel, uniform across waves. Per-node
// accumulation order unchanged -> numerics identical.
// l2 epilogue (out-proj+softmax, ~16 MFMA) runs on wave 0 only; wave 1
// retires after its last barrier.
//
// CSR build (R7): phase A dumps each block's 2048 LDS-sorted edges into its
// own 8KB slab (coalesced) + packed (start|end<<16) bucket offsets; no
// global atomics, no memset. fill_csr: block bk walks slabs, reads its runs,
// LDS-atomic place, 32KB coalesced dump + capped cnt.
//
// Dual GEMM as one K=256 MFMA GEMM: A_cat=[agg|root] bf16, W_cat=[Wl;Wr] packed.
// mfma_f32_16x16x32_bf16: A[m=lane&15][k=(lane>>4)*8+j]; B[k][n=lane&15];
// C: col=lane&15, row=(lane>>4)*4+reg (m89/m91-verified layouts).

#define CAP 64
#define NBK 256      // bucket table stride (max buckets; N<=65536)
#define EPB 2048     // edges per phase-A block (8 per thread) = one slab
#define ASTR 136     // LDS A-tile row stride in ushorts (272B = 17x16B)

typedef __attribute__((ext_vector_type(8))) short bf16x8;
typedef __attribute__((ext_vector_type(4))) float f32x4;

__device__ __forceinline__ unsigned short bf16_rtne(float f) {
    unsigned u = __float_as_uint(f);
    u += 0x7FFFu + ((u >> 16) & 1u);
    return (unsigned short)(u >> 16);
}

__device__ __forceinline__ unsigned pack2(float lo, float hi) {
    return (unsigned)bf16_rtne(lo) | ((unsigned)bf16_rtne(hi) << 16);
}

__device__ __forceinline__ void pack_w_body(const float* __restrict__ Wl,
                                            const float* __restrict__ Wr,
                                            unsigned short* __restrict__ Wp, int i) {
    int j = i & 7;
    int l = (i >> 3) & 63;
    int ntile = (i >> 9) & 7;
    int kstep = i >> 12;
    int k = kstep * 32 + (l >> 4) * 8 + j;
    int n = ntile * 16 + (l & 15);
    float v = (k < 128) ? Wl[k * 128 + n] : Wr[(k - 128) * 128 + n];
    Wp[i] = bf16_rtne(v);
}

// Fused dispatch 1: [phase-A bucket-sort + slab dump | cvt x->bf16 | pack W].
__global__ __launch_bounds__(256) void bucket_prep_kernel(
        const int* __restrict__ src, const int* __restrict__ dst,
        unsigned int* __restrict__ pref2, unsigned int* __restrict__ gbuf,
        int E, int aBlocks,
        const float* __restrict__ x, unsigned short* __restrict__ xb, int n4, int cvtBlocks,
        const float* __restrict__ Wl0, const float* __restrict__ Wr0,
        unsigned short* __restrict__ Wp1,
        const float* __restrict__ Wl1, const float* __restrict__ Wr1,
        unsigned short* __restrict__ Wp2,
        const float* __restrict__ Wout, unsigned short* __restrict__ Wpo) {
    int b = blockIdx.x;
    if (b < aBlocks) {
        __shared__ unsigned int hist[NBK];
        __shared__ unsigned int pref[NBK + 1];
        __shared__ unsigned int scat[EPB];      // 8 KB slab image
        int tid = (int)threadIdx.x;
        hist[tid] = 0u;
        __syncthreads();

        int e0 = b * EPB + tid * 8;
        int dd[8], ss[8], bb[8];
        unsigned rr[8];
        bool vld[8];
        if (e0 + 7 < E) {
            int4 d0 = *(const int4*)(dst + e0);
            int4 d1 = *(const int4*)(dst + e0 + 4);
            int4 s0 = *(const int4*)(src + e0);
            int4 s1 = *(const int4*)(src + e0 + 4);
            dd[0] = d0.x; dd[1] = d0.y; dd[2] = d0.z; dd[3] = d0.w;
            dd[4] = d1.x; dd[5] = d1.y; dd[6] = d1.z; dd[7] = d1.w;
            ss[0] = s0.x; ss[1] = s0.y; ss[2] = s0.z; ss[3] = s0.w;
            ss[4] = s1.x; ss[5] = s1.y; ss[6] = s1.z; ss[7] = s1.w;
#pragma unroll
            for (int u = 0; u < 8; ++u) vld[u] = true;
        } else {
#pragma unroll
            for (int u = 0; u < 8; ++u) {
                int e = e0 + u;
                vld[u] = (e < E);
                dd[u] = vld[u] ? dst[e] : 0;
                ss[u] = vld[u] ? src[e] : 0;
            }
        }
#pragma unroll
        for (int u = 0; u < 8; ++u) {
            bb[u] = dd[u] >> 8;
            rr[u] = vld[u] ? atomicAdd(&hist[bb[u]], 1u) : 0u;
        }
        __syncthreads();
        // exclusive prefix over hist: pref[i] = sum hist[0..i-1] (Hillis-Steele)
        pref[tid + 1] = hist[tid];
        if (tid == 0) pref[0] = 0u;
        __syncthreads();
        for (int off = 1; off < NBK; off <<= 1) {
            unsigned add = (tid + 1 > off) ? pref[tid + 1 - off] : 0u;
            __syncthreads();
            pref[tid + 1] += add;
            __syncthreads();
        }
        // local bucket-sort into the slab image
#pragma unroll
        for (int u = 0; u < 8; ++u) {
            if (vld[u]) {
                unsigned idx = pref[bb[u]] + rr[u];
                scat[idx] = ((unsigned)dd[u] << 16) | (unsigned)(ss[u] & 0xFFFF);
            }
        }
        __syncthreads();
        // coalesced slab dump: full 8KB burst (tail garbage never read)
        {
            uint4* g4 = (uint4*)(gbuf + (size_t)b * EPB);
            const uint4* s4 = (const uint4*)scat;
            for (int i = tid; i < EPB / 4; i += 256) g4[i] = s4[i];
        }
        // packed per-bucket offsets: (start | end<<16), both <= 2048 (fit u16)
        pref2[(size_t)b * NBK + tid] = (pref[tid] & 0xFFFFu) | (pref[tid + 1] << 16);
    } else if (b < aBlocks + cvtBlocks) {
        int i = (b - aBlocks) * 256 + (int)threadIdx.x;
        if (i < n4) {
            float4 v = ((const float4*)x)[i];
            ushort4 o;
            o.x = bf16_rtne(v.x); o.y = bf16_rtne(v.y);
            o.z = bf16_rtne(v.z); o.w = bf16_rtne(v.w);
            ((ushort4*)xb)[i] = o;
        }
    } else if (b < aBlocks + cvtBlocks + 128) {
        pack_w_body(Wl0, Wr0, Wp1, (b - aBlocks - cvtBlocks) * 256 + (int)threadIdx.x);
    } else if (b < aBlocks + cvtBlocks + 256) {
        pack_w_body(Wl1, Wr1, Wp2, (b - aBlocks - cvtBlocks - 128) * 256 + (int)threadIdx.x);
    } else {
        int i = (b - aBlocks - cvtBlocks - 256) * 256 + (int)threadIdx.x;   // 32 blocks
        int j = i & 7;
        int l = (i >> 3) & 63;
        int nt = (i >> 9) & 3;
        int ks = i >> 11;
        int k = ks * 32 + (l >> 4) * 8 + j;
        int n = nt * 16 + (l & 15);
        Wpo[i] = bf16_rtne(Wout[k * 64 + n]);
    }
}

// One block per 256-node bucket: walk all slabs, read this bucket's run from
// each (scattered ~40B reads; latency-tolerant), place via LDS atomics into
// the stage, dump 32KB coalesced + capped cnt. No global atomics, one pass.
__global__ __launch_bounds__(256) void fill_csr_kernel(
        const unsigned int* __restrict__ pref2, const unsigned int* __restrict__ gbuf,
        int* __restrict__ cnt, unsigned short* __restrict__ csr, int N, int aBlocks) {
    __shared__ unsigned int cntL[256];            // 1 KB
    __shared__ unsigned short stage[256 * CAP];   // 32 KB; garbage beyond deg never read
    int bk = blockIdx.x;
    int tid = (int)threadIdx.x;
    cntL[tid] = 0u;
    __syncthreads();
    for (int b = tid; b < aBlocks; b += 256) {
        unsigned pr = pref2[(size_t)b * NBK + bk];
        unsigned st = pr & 0xFFFFu;
        unsigned en = pr >> 16;
        const unsigned int* slab = gbuf + (size_t)b * EPB;
        for (unsigned i = st; i < en; ++i) {
            unsigned pk = slab[i];
            int dl = (int)((pk >> 16) & 255u);
            unsigned p = atomicAdd(&cntL[dl], 1u);
            if (p < CAP) stage[dl * CAP + p] = (unsigned short)(pk & 0xFFFFu);
        }
    }
    __syncthreads();
    const uint4* s4 = (const uint4*)stage;
    uint4* g4 = (uint4*)(csr + (size_t)bk * (256 * CAP));
    for (int i = tid; i < (256 * CAP) / 8; i += 256) g4[i] = s4[i];
    int node = bk * 256 + tid;
    if (node < N) cnt[node] = min((int)cntL[tid], CAP);
}

// Co-gather: wave wv gathers rows wv*8..wv*8+7 of the block's 16-node tile.
// Inner loop = R2/R5 verbatim (dense clamped 256B uint4 loads, 8 in flight
// per quarter-wave); each quarter-wave handles 2 nodes. Per-node accumulation
// order unchanged -> numerics identical to previous rounds.
__device__ __forceinline__ void gather_mean_lds2(
        const uint4* __restrict__ h4,          // bf16 table, one row = 16 uint4
        const int* __restrict__ cnt,
        const unsigned short* __restrict__ csr, unsigned short* __restrict__ sAw,
        int m0, int wv, int lane, int N) {
    int qw = lane >> 4;      // quarter-wave 0..3
    int ql = lane & 15;
#pragma unroll 1
    for (int i = 0; i < 2; ++i) {
        int nl = wv * 8 + qw * 2 + i;
        int node = m0 + nl;
        int deg = (node < N) ? min(cnt[node], CAP) : 0;
        int s0 = node * CAP;
        int s1 = s0 + deg;
        float a[8];
#pragma unroll
        for (int u = 0; u < 8; ++u) a[u] = 0.f;
        for (int base = 0; base < deg; base += 16) {
            int nc = min(16, deg - base);
            int e = min(s0 + base + ql, s1 - 1);
            int idx = csr[e];
            for (int j = 0; j < nc; j += 8) {
                uint4 v[8];
#pragma unroll
                for (int u = 0; u < 8; ++u) {
                    int sidx = __shfl(idx, j + u, 16);
                    v[u] = h4[(size_t)sidx * 16 + ql];
                }
#pragma unroll
                for (int u = 0; u < 8; ++u) {
                    bool ok = (j + u < nc);
                    unsigned w0 = ok ? v[u].x : 0u;
                    unsigned w1 = ok ? v[u].y : 0u;
                    unsigned w2 = ok ? v[u].z : 0u;
                    unsigned w3 = ok ? v[u].w : 0u;
                    a[0] += __uint_as_float(w0 << 16);
                    a[1] += __uint_as_float(w0 & 0xFFFF0000u);
                    a[2] += __uint_as_float(w1 << 16);
                    a[3] += __uint_as_float(w1 & 0xFFFF0000u);
                    a[4] += __uint_as_float(w2 << 16);
                    a[5] += __uint_as_float(w2 & 0xFFFF0000u);
                    a[6] += __uint_as_float(w3 << 16);
                    a[7] += __uint_as_float(w3 & 0xFFFF0000u);
                }
            }
        }
        float inv = 1.0f / (float)max(deg, 1);
        uint4 o;
        o.x = pack2(a[0] * inv, a[1] * inv);
        o.y = pack2(a[2] * inv, a[3] * inv);
        o.z = pack2(a[4] * inv, a[5] * inv);
        o.w = pack2(a[6] * inv, a[7] * inv);
        *(uint4*)(sAw + nl * ASTR + ql * 8) = o;   // 272B row -> bank-floor reads
    }
}

// Half-split MFMA core: wave wv computes ntiles wv*4..wv*4+3 of the 16x128
// output (K=256: [aggLDS | rootGlobal]); acc[4] per wave.
__device__ __forceinline__ void mfma_dual_gemm_half(
        const unsigned short* __restrict__ sAw, const unsigned short* __restrict__ rootb,
        const unsigned short* __restrict__ Wp, int rowc, int quad, int c, int lane,
        int wv, f32x4 acc[4]) {
#pragma unroll
    for (int t = 0; t < 4; ++t) acc[t] = (f32x4){0.f, 0.f, 0.f, 0.f};
    for (int ks = 0; ks < 8; ++ks) {
        bf16x8 a;
        if (ks < 4) a = *(const bf16x8*)(sAw + c * ASTR + ks * 32 + quad * 8);
        else        a = *(const bf16x8*)(rootb + (size_t)rowc * 128 + (ks & 3) * 32 + quad * 8);
#pragma unroll
        for (int t = 0; t < 4; ++t) {
            int tt = wv * 4 + t;
            bf16x8 bf = *(const bf16x8*)(Wp + ((size_t)(ks * 8 + tt) * 64 + lane) * 8);
            acc[t] = __builtin_amdgcn_mfma_f32_16x16x32_bf16(a, bf, acc[t], 0, 0, 0);
        }
    }
}

// Layer 1: h0 = relu(mean_agg(x)@Wl + x@Wr + b) -> bf16 store.
// 128 threads / 16-node tile. Barriers: gather->GEMM, GEMM->tile-overwrite,
// overwrite->dump. h0 dumped as coalesced 256B rows.
__global__ __launch_bounds__(128) void fused_l1_kernel(
        const unsigned short* __restrict__ hb, const int* __restrict__ cnt,
        const unsigned short* __restrict__ csr, const unsigned short* __restrict__ Wp,
        const float* __restrict__ b, unsigned short* __restrict__ houtb, int N) {
    __shared__ unsigned short sA[16 * ASTR];   // 4.25 KB shared tile
    int tid = (int)threadIdx.x;
    int lane = tid & 63;
    int wv = tid >> 6;                          // 0..1
    int m0 = blockIdx.x * 16;
    gather_mean_lds2((const uint4*)hb, cnt, csr, sA, m0, wv, lane, N);
    __syncthreads();
    int quad = lane >> 4;
    int c = lane & 15;
    int rowc = min(m0 + c, N - 1);
    f32x4 acc[4];
    mfma_dual_gemm_half(sA, hb, Wp, rowc, quad, c, lane, wv, acc);
    __syncthreads();   // both waves done reading the A-tile
    // relu+bias -> sA (each wave writes its 64-col half)
#pragma unroll
    for (int t = 0; t < 4; ++t) {
        int col = (wv * 4 + t) * 16 + c;
        float bias = b[col];
#pragma unroll
        for (int r = 0; r < 4; ++r) {
            sA[(quad * 4 + r) * ASTR + col] = bf16_rtne(fmaxf(acc[t][r] + bias, 0.f));
        }
    }
    __syncthreads();
    // coalesced dump: 16 rows x 16 uint4 = 256 chunks over 128 threads
#pragma unroll
    for (int it = 0; it < 2; ++it) {
        int chunk = it * 128 + tid;
        int row = chunk >> 4;
        int ql = chunk & 15;
        int node = m0 + row;
        if (node < N) {
            uint4 rv = *(const uint4*)(&sA[row * ASTR + ql * 8]);
            *(uint4*)(houtb + (size_t)node * 128 + ql * 8) = rv;
        }
    }
}

// Layer 2 + out-projection + softmax. Both waves write h1 into the shared
// tile; wave 0 runs the small out-proj (16 MFMA) + softmax + store alone
// (wave 1 retires after its last barrier).
__global__ __launch_bounds__(128) void fused_l2_kernel(
        const unsigned short* __restrict__ hb, const int* __restrict__ cnt,
        const unsigned short* __restrict__ csr, const unsigned short* __restrict__ Wp,
        const float* __restrict__ b,
        const unsigned short* __restrict__ Wpo, const float* __restrict__ bout,
        float* __restrict__ out, int N) {
    __shared__ unsigned short sA[16 * ASTR];   // 4.25 KB, reused for h1 tile
    int tid = (int)threadIdx.x;
    int lane = tid & 63;
    int wv = tid >> 6;
    int m0 = blockIdx.x * 16;
    gather_mean_lds2((const uint4*)hb, cnt, csr, sA, m0, wv, lane, N);
    __syncthreads();
    int quad = lane >> 4;
    int c = lane & 15;
    int rowc = min(m0 + c, N - 1);
    f32x4 acc[4];
    mfma_dual_gemm_half(sA, hb, Wp, rowc, quad, c, lane, wv, acc);
    __syncthreads();   // both waves done reading the A-tile
    // relu -> h1 tile (each wave its 64-col half)
#pragma unroll
    for (int t = 0; t < 4; ++t) {
        int col = (wv * 4 + t) * 16 + c;
        float bias = b[col];
#pragma unroll
        for (int r = 0; r < 4; ++r) {
            sA[(quad * 4 + r) * ASTR + col] = bf16_rtne(fmaxf(acc[t][r] + bias, 0.f));
        }
    }
    __syncthreads();   // h1 tile complete (last barrier: uniform across waves)
    if (wv != 0) return;

    // out = h1 @ Wout : K=128 (4 ksteps), N=64 (4 ntiles) -> 16 MFMAs (wave 0).
    f32x4 acc2[4];
#pragma unroll
    for (int nt = 0; nt < 4; ++nt) acc2[nt] = (f32x4){0.f, 0.f, 0.f, 0.f};
#pragma unroll
    for (int ks = 0; ks < 4; ++ks) {
        bf16x8 a = *(const bf16x8*)&sA[c * ASTR + ks * 32 + quad * 8];
#pragma unroll
        for (int nt = 0; nt < 4; ++nt) {
            bf16x8 bf = *(const bf16x8*)(Wpo + ((size_t)(ks * 4 + nt) * 64 + lane) * 8);
            acc2[nt] = __builtin_amdgcn_mfma_f32_16x16x32_bf16(a, bf, acc2[nt], 0, 0, 0);
        }
    }

    // softmax: row m=quad*4+r lives in a 16-lane group x 4 regs (nt).
    float bo[4];
#pragma unroll
    for (int nt = 0; nt < 4; ++nt) bo[nt] = bout[nt * 16 + c];
#pragma unroll
    for (int r = 0; r < 4; ++r) {
        float v[4];
#pragma unroll
        for (int nt = 0; nt < 4; ++nt) v[nt] = acc2[nt][r] + bo[nt];
        float m = fmaxf(fmaxf(v[0], v[1]), fmaxf(v[2], v[3]));
#pragma unroll
        for (int ofs = 1; ofs < 16; ofs <<= 1) m = fmaxf(m, __shfl_xor(m, ofs, 64));
        float e[4];
        float s = 0.f;
#pragma unroll
        for (int nt = 0; nt < 4; ++nt) { e[nt] = __expf(v[nt] - m); s += e[nt]; }
#pragma unroll
        for (int ofs = 1; ofs < 16; ofs <<= 1) s += __shfl_xor(s, ofs, 64);
        float inv = 1.0f / s;
        int node = m0 + quad * 4 + r;
        if (node < N) {
#pragma unroll
            for (int nt = 0; nt < 4; ++nt)
                out[(size_t)node * 64 + nt * 16 + c] = e[nt] * inv;
        }
    }
}

extern "C" void kernel_launch(void* const* d_in, const int* in_sizes, int n_in,
                              void* d_out, int out_size, void* d_ws, size_t ws_size,
                              hipStream_t stream) {
    const float* x    = (const float*)d_in[0];
    const int*   ei   = (const int*)d_in[1];
    const float* Wl0  = (const float*)d_in[2];
    const float* Wr0  = (const float*)d_in[3];
    const float* b0   = (const float*)d_in[4];
    const float* Wl1  = (const float*)d_in[5];
    const float* Wr1  = (const float*)d_in[6];
    const float* b1   = (const float*)d_in[7];
    const float* Wout = (const float*)d_in[8];
    const float* bout = (const float*)d_in[9];

    int N = in_sizes[0] / 128;
    int E = in_sizes[1] / 2;
    const int* src = ei;
    const int* dst = ei + E;
    int nb = (N + 255) >> 8;             // node buckets (256 nodes each)
    int aBlocks = (E + EPB - 1) / EPB;   // phase-A blocks = slabs

    char* p = (char*)d_ws;
    auto alloc = [&](size_t bytes) -> char* {
        char* r = p;
        p += (bytes + 255) & ~(size_t)255;
        return r;
    };
    unsigned int*   pref2 = (unsigned int*)alloc((size_t)aBlocks * NBK * 4);
    unsigned int*   gbuf  = (unsigned int*)alloc((size_t)aBlocks * EPB * 4);
    int*            cnt   = (int*)alloc((size_t)N * 4);
    unsigned short* csr   = (unsigned short*)alloc((size_t)nb * 256 * CAP * 2);
    unsigned short* xb    = (unsigned short*)alloc((size_t)N * 128 * 2);
    unsigned short* h0b   = (unsigned short*)alloc((size_t)N * 128 * 2);
    unsigned short* Wp1   = (unsigned short*)alloc((size_t)32768 * 2);
    unsigned short* Wp2   = (unsigned short*)alloc((size_t)32768 * 2);
    unsigned short* Wpo   = (unsigned short*)alloc((size_t)8192 * 2);

    int n4 = N * 128 / 4;
    int cvtBlocks = (n4 + 255) / 256;
    bucket_prep_kernel<<<aBlocks + cvtBlocks + 256 + 32, 256, 0, stream>>>(
        src, dst, pref2, gbuf, E, aBlocks,
        x, xb, n4, cvtBlocks, Wl0, Wr0, Wp1, Wl1, Wr1, Wp2, Wout, Wpo);

    fill_csr_kernel<<<nb, 256, 0, stream>>>(pref2, gbuf, cnt, csr, N, aBlocks);

    int gb = (N + 15) / 16;          // fused: 16 nodes/block (2 waves co-gather)
    fused_l1_kernel<<<gb, 128, 0, stream>>>(xb, cnt, csr, Wp1, b0, h0b, N);
    fused_l2_kernel<<<gb, 128, 0, stream>>>(h0b, cnt, csr, Wp2, b1,
                                            Wpo, bout, (float*)d_out, N);
}